// Round 5
// baseline (667.155 us; speedup 1.0000x reference)
//
#include <hip/hip_runtime.h>
#include <hip/hip_bf16.h>
#include <hip/hip_fp16.h>

// Problem: y[b,s,o] = sum_i x[b,s,i] * w[o,i] + bias[o]
//   w = weight_high + fp32(weight_medium) + (~high & ~medium) * weight_low * low_scale
// M = 4*2048 = 8192, N = 4096, K = 4096.
// Round 5: faithful port of the 8-phase 256^2 template (m201 class, measured
// 62% MfmaUtil): BK=64, 2 LDS double-buffers (128 KiB), 4 phases per K-tile,
// each phase {ds_read subtile + 2 staged global_load_lds -> barrier ->
// lgkmcnt(0) -> setprio -> 16 MFMA -> setprio -> barrier}; ONE vmcnt per
// K-tile at iter top (drains only iteration-old loads). Swizzle for 128B rows:
// byte ^= (row&7)<<4, applied on pre-swizzled global source AND ds_read.

#define M_DIM 8192
#define N_DIM 4096
#define K_DIM 4096

typedef __attribute__((ext_vector_type(8))) short short8;
typedef __attribute__((ext_vector_type(4))) float floatx4;
typedef __attribute__((ext_vector_type(8))) _Float16 half8;
typedef __attribute__((ext_vector_type(8))) unsigned char uchar8;
typedef __attribute__((ext_vector_type(4))) int intx4;

__device__ inline unsigned short f2bf(float f) {
    union { float f; unsigned u; } v; v.f = f;
    return (unsigned short)((v.u + 0x7fffu + ((v.u >> 16) & 1u)) >> 16);  // RNE
}

__device__ inline void async16(const void* g, const void* l) {
    __builtin_amdgcn_global_load_lds(
        (const __attribute__((address_space(1))) void*)g,
        (__attribute__((address_space(3))) void*)l,
        16, 0, 0);
}

// ---------- fused prep: dtype-detect (per-block ballot) + w reconstruct + x cvt ----------
// blocks [0, 8192)     : wbf[i] = bf16(wh + wm + lowmask*wl*scale), 8 elems/thread
// blocks [8192, 24576) : xbf[i] = bf16(x[i]), 8 elems/thread
__global__ __launch_bounds__(256) void prep_kernel(
        const float* __restrict__ x,
        const float* __restrict__ wh, const void* __restrict__ wm_raw,
        const int* __restrict__ wl, const void* __restrict__ hm_raw,
        const void* __restrict__ mm_raw, const float* __restrict__ scale_p,
        unsigned short* __restrict__ wbf, unsigned short* __restrict__ xbf) {
    const int bid = blockIdx.x;
    const int tid = threadIdx.x;

    if (bid >= 8192) {
        const size_t i = ((size_t)(bid - 8192) * 256 + tid) * 8;
        floatx4 f0 = *(const floatx4*)(x + i);
        floatx4 f1 = *(const floatx4*)(x + i + 4);
        short8 s;
        s[0] = (short)f2bf(f0[0]); s[1] = (short)f2bf(f0[1]);
        s[2] = (short)f2bf(f0[2]); s[3] = (short)f2bf(f0[3]);
        s[4] = (short)f2bf(f1[0]); s[5] = (short)f2bf(f1[1]);
        s[6] = (short)f2bf(f1[2]); s[7] = (short)f2bf(f1[3]);
        *(short8*)(xbf + i) = s;
        return;
    }

    // dtype flags from the first 64 words (L2 broadcast, per-block ballot)
    const int lane = tid & 63;
    union { unsigned u; float f; } pw; pw.u = ((const unsigned*)wm_raw)[lane];
    const float pav = fabsf(pw.f);
    const bool wm_f32  = __popcll(__ballot(pav > 1e-4f && pav < 1.0f)) >= 4;
    const bool mask_u8 = __ballot(((const unsigned*)hm_raw)[lane] > 1u) != 0;

    const size_t i = ((size_t)bid * 256 + tid) * 8;
    const float scale = *scale_p;

    floatx4 h0 = *(const floatx4*)(wh + i);
    floatx4 h1 = *(const floatx4*)(wh + i + 4);
    intx4  l0 = *(const intx4*)(wl + i);
    intx4  l1 = *(const intx4*)(wl + i + 4);

    float mv[8];
    if (wm_f32) {
        floatx4 m0 = *(const floatx4*)((const float*)wm_raw + i);
        floatx4 m1 = *(const floatx4*)((const float*)wm_raw + i + 4);
#pragma unroll
        for (int e = 0; e < 4; ++e) { mv[e] = m0[e]; mv[e + 4] = m1[e]; }
    } else {
        half8 m = *(const half8*)((const _Float16*)wm_raw + i);
#pragma unroll
        for (int e = 0; e < 8; ++e) mv[e] = (float)m[e];
    }

    int lowmask[8];
    if (mask_u8) {
        uchar8 a = *(const uchar8*)((const unsigned char*)hm_raw + i);
        uchar8 b = *(const uchar8*)((const unsigned char*)mm_raw + i);
#pragma unroll
        for (int e = 0; e < 8; ++e) lowmask[e] = (a[e] | b[e]) == 0;
    } else {
        intx4 a0 = *(const intx4*)((const int*)hm_raw + i);
        intx4 a1 = *(const intx4*)((const int*)hm_raw + i + 4);
        intx4 b0 = *(const intx4*)((const int*)mm_raw + i);
        intx4 b1 = *(const intx4*)((const int*)mm_raw + i + 4);
#pragma unroll
        for (int e = 0; e < 4; ++e) {
            lowmask[e]     = (a0[e] | b0[e]) == 0;
            lowmask[e + 4] = (a1[e] | b1[e]) == 0;
        }
    }

    short8 s;
#pragma unroll
    for (int e = 0; e < 8; ++e) {
        float v = (e < 4 ? h0[e] : h1[e - 4]) + mv[e];
        int   lw = (e < 4 ? l0[e] : l1[e - 4]);
        if (lowmask[e]) v += (float)lw * scale;
        s[e] = (short)f2bf(v);
    }
    *(short8*)(wbf + i) = s;
}

// ---------- 256x256 GEMM, 8-phase template: BK=64, 2 dbufs, 4 phases/K-tile ----------
// C[m,n] = sum_k A[m,k]*B[n,k] + bias[n] (A,B bf16 row-major [*,K], C fp32)
// 512 threads = 8 waves (2M x 4N); per-wave output 128x64; MFMA 16x16x32.
// LDS: 2 dbufs x 64 KiB (A[256][64] @ +0, B[256][64] @ +32768) = 128 KiB.
// dbuf layout: linear rows of 128B; content pre-swizzled so that
//   value(row, col_byte) lives at row*128 + (col_byte ^ ((row&7)<<4)).
// Staging (8 x async16/thread/K-tile, sprinkled 2 per phase): HW writes lane l
// at uniform_base + l*16 -> byte p = c*8192 + tid*16 -> row = c*64 + tid>>3,
// in-row = (tid&7)*16; source column pre-XOR'd by ((tid>>3)&7)<<4.
// Reads: frag addr = row*128 + ((lquad*16 + ks*64) ^ ((row&7)<<4)); lanes 0-15
// spread over 8 distinct 16B slots (2-way residual = free, m136).
// Ledger: stage(t+1) -> dbuf[(t+1)&1], whose last reads (tile t-1) ended before
// iter t's top barrier. WAITV(0) at iter-t top drains tile t's 8 loads, all
// issued >= 1 phase earlier in iter t-1 (T4: never stall on recent loads);
// phases carry no vmem waits at all.
__global__ __launch_bounds__(512, 2) void gemm256_kernel(
        const unsigned short* __restrict__ A,   // [M,K] bf16
        const unsigned short* __restrict__ Bw,  // [N,K] bf16
        const float* __restrict__ bias,
        float* __restrict__ out) {
    extern __shared__ char smem[];
    const int tid  = threadIdx.x;
    const int wave = tid >> 6, lane = tid & 63;
    const int lrow = lane & 15, lquad = lane >> 4;

    // XCD-bijective swizzle: 512 blocks, 64 per XCD; bn varies fastest within
    // an XCD so co-resident blocks share the A panel in L2.
    const int wg  = blockIdx.x;
    const int swz = (wg & 7) * 64 + (wg >> 3);
    const int bm0 = (swz >> 4) * 256;   // 32 row-tiles
    const int bn0 = (swz & 15) * 256;   // 16 col-tiles

    const int wr = wave >> 2, wc = wave & 3;
    const int wm = wr * 128, wn = wc * 64;

    // staging: linear LDS dest (uniform base; HW adds lane*16), pre-swizzled src
    const int srow = tid >> 3;                              // 0..63 within c-group
    const int scel = ((tid & 7) ^ ((tid >> 3) & 7)) << 3;   // pre-swizzled elem col
    const unsigned short* gA = A  + (size_t)(bm0 + srow) * K_DIM + scel;
    const unsigned short* gB = Bw + (size_t)(bn0 + srow) * K_DIM + scel;
    const int dstU = wave * 1024;

    // swizzled read byte offsets (ks = 32-k slice 0/1); frag i adds i*2048
    int offA[2], offB[2];
#pragma unroll
    for (int ks = 0; ks < 2; ++ks) {
        const int xa = (lquad * 16 + ks * 64) ^ ((lrow & 7) << 4);
        offA[ks] = (wm + lrow) * 128 + xa;
        offB[ks] = 32768 + (wn + lrow) * 128 + xa;
    }

    floatx4 acc[8][4] = {};
    short8 afT[4], bq0[4], bq1[4];

#define STGA(T, C) async16(gA + (size_t)(C) * 64 * K_DIM + (unsigned)(T) * 64u, \
                           smem + (((T) & 1) << 16) + (C) * 8192 + dstU)
#define STGB(T, C) async16(gB + (size_t)(C) * 64 * K_DIM + (unsigned)(T) * 64u, \
                           smem + (((T) & 1) << 16) + 32768 + (C) * 8192 + dstU)

#define RD4A(DB, KS, IH) do { _Pragma("unroll") \
    for (int i_ = 0; i_ < 4; ++i_) \
        afT[i_] = *(const short8*)((DB) + offA[KS] + ((IH) + i_) * 2048); } while (0)
#define RD4B(BQ, DB, KS) do { _Pragma("unroll") \
    for (int j_ = 0; j_ < 4; ++j_) \
        BQ[j_] = *(const short8*)((DB) + offB[KS] + j_ * 2048); } while (0)

#define MM16(BQ, IH) do { \
    __builtin_amdgcn_s_setprio(1); \
    _Pragma("unroll") \
    for (int i_ = 0; i_ < 4; ++i_) \
        _Pragma("unroll") \
        for (int j_ = 0; j_ < 4; ++j_) \
            acc[(IH) + i_][j_] = __builtin_amdgcn_mfma_f32_16x16x32_bf16( \
                afT[i_], BQ[j_], acc[(IH) + i_][j_], 0, 0, 0); \
    __builtin_amdgcn_s_setprio(0); } while (0)

#define WAITV0() asm volatile("s_waitcnt vmcnt(0)" ::: "memory")
#define LGKM0()  asm volatile("s_waitcnt lgkmcnt(0)" ::: "memory")
#define BARX() do { __builtin_amdgcn_s_barrier(); asm volatile("" ::: "memory"); } while (0)
#define SCHED0() __builtin_amdgcn_sched_barrier(0)

// One K-tile(64): 4 phases, each {reads + 2 stage-issues, BAR, lgkm0, 16 MFMA,
// BAR}; phase-3 trailing barrier folds into the next iter's top barrier.
#define ITER(T, DOST) do { \
    WAITV0(); \
    BARX(); \
    const char* db_ = smem + (((T) & 1) << 16); \
    /* phase 0: A[0..3]ks0 + B ks0 ; stage A c0,c1 of t+1 */ \
    RD4A(db_, 0, 0); RD4B(bq0, db_, 0); \
    if (DOST) { STGA((T) + 1, 0); STGA((T) + 1, 1); } \
    SCHED0(); BARX(); LGKM0(); SCHED0(); \
    MM16(bq0, 0); \
    BARX(); \
    /* phase 1: A[4..7]ks0 ; stage A c2,c3 */ \
    RD4A(db_, 0, 4); \
    if (DOST) { STGA((T) + 1, 2); STGA((T) + 1, 3); } \
    SCHED0(); BARX(); LGKM0(); SCHED0(); \
    MM16(bq0, 4); \
    BARX(); \
    /* phase 2: A[0..3]ks1 + B ks1 ; stage B c0,c1 */ \
    RD4A(db_, 1, 0); RD4B(bq1, db_, 1); \
    if (DOST) { STGB((T) + 1, 0); STGB((T) + 1, 1); } \
    SCHED0(); BARX(); LGKM0(); SCHED0(); \
    MM16(bq1, 0); \
    BARX(); \
    /* phase 3: A[4..7]ks1 ; stage B c2,c3 */ \
    RD4A(db_, 1, 4); \
    if (DOST) { STGB((T) + 1, 2); STGB((T) + 1, 3); } \
    SCHED0(); BARX(); LGKM0(); SCHED0(); \
    MM16(bq1, 4); \
} while (0)

    // prologue: tile 0 -> dbuf0 (8 loads/thread)
    STGA(0, 0); STGA(0, 1); STGA(0, 2); STGA(0, 3);
    STGB(0, 0); STGB(0, 1); STGB(0, 2); STGB(0, 3);

    const int NT = K_DIM / 64;  // 64
    for (int t = 0; t < NT - 1; ++t)
        ITER(t, true);
    ITER(NT - 1, false);

#undef STGA
#undef STGB
#undef RD4A
#undef RD4B
#undef MM16
#undef WAITV0
#undef LGKM0
#undef BARX
#undef SCHED0
#undef ITER

    // epilogue (verified 16x16 C/D layout: col = lane&15, row = lquad*4 + r)
#pragma unroll
    for (int j = 0; j < 4; ++j) {
        const int col = bn0 + wn + j * 16 + lrow;
        const float bv = bias[col];
#pragma unroll
        for (int i = 0; i < 8; ++i) {
            const int row = bm0 + wm + i * 16 + lquad * 4;
#pragma unroll
            for (int r = 0; r < 4; ++r)
                out[(size_t)(row + r) * N_DIM + col] = acc[i][j][r] + bv;
        }
    }
}

// ---------- fallback: A staged from fp32 inline (small-ws path) ----------
__global__ __launch_bounds__(256) void gemm_fused_kernel(
        const float* __restrict__ X,            // [M,K] fp32
        const unsigned short* __restrict__ Bw,  // [N,K] bf16
        const float* __restrict__ bias,
        float* __restrict__ out) {
    __shared__ unsigned short As[128 * 32];
    __shared__ unsigned short Bs[128 * 32];
    const int tid  = threadIdx.x;
    const int wave = tid >> 6, lane = tid & 63;
    const int bm0 = blockIdx.y * 128, bn0 = blockIdx.x * 128;
    const int wm = (wave >> 1) * 64, wn = (wave & 1) * 64;
    const int lrow = lane & 15, lquad = lane >> 4;
    const int arow = tid >> 1, acol = (tid & 1) * 16;

    floatx4 acc[4][4] = {};

    for (int k0 = 0; k0 < K_DIM; k0 += 32) {
        __syncthreads();
#pragma unroll
        for (int c = 0; c < 2; ++c) {
            const int lb  = wave * 2048 + c * 1024;
            const int e   = (lb >> 1) + lane * 8;
            const int row = e >> 5, col = e & 31;
            async16(Bw + (size_t)(bn0 + row) * K_DIM + k0 + col, (const char*)Bs + lb);
        }
        {
            const float* g = X + (size_t)(bm0 + arow) * K_DIM + k0 + acol;
            floatx4 f0 = *(const floatx4*)(g);
            floatx4 f1 = *(const floatx4*)(g + 4);
            floatx4 f2 = *(const floatx4*)(g + 8);
            floatx4 f3 = *(const floatx4*)(g + 12);
            short8 s0, s1;
            s0[0]=(short)f2bf(f0[0]); s0[1]=(short)f2bf(f0[1]); s0[2]=(short)f2bf(f0[2]); s0[3]=(short)f2bf(f0[3]);
            s0[4]=(short)f2bf(f1[0]); s0[5]=(short)f2bf(f1[1]); s0[6]=(short)f2bf(f1[2]); s0[7]=(short)f2bf(f1[3]);
            s1[0]=(short)f2bf(f2[0]); s1[1]=(short)f2bf(f2[1]); s1[2]=(short)f2bf(f2[2]); s1[3]=(short)f2bf(f2[3]);
            s1[4]=(short)f2bf(f3[0]); s1[5]=(short)f2bf(f3[1]); s1[6]=(short)f2bf(f3[2]); s1[7]=(short)f2bf(f3[3]);
            *(short8*)&As[arow * 32 + acol]     = s0;
            *(short8*)&As[arow * 32 + acol + 8] = s1;
        }
        __syncthreads();

        short8 af[4], bf[4];
#pragma unroll
        for (int i = 0; i < 4; ++i)
            af[i] = *(const short8*)&As[(wm + i * 16 + lrow) * 32 + lquad * 8];
#pragma unroll
        for (int j = 0; j < 4; ++j)
            bf[j] = *(const short8*)&Bs[(wn + j * 16 + lrow) * 32 + lquad * 8];
#pragma unroll
        for (int i = 0; i < 4; ++i)
#pragma unroll
            for (int j = 0; j < 4; ++j)
                acc[i][j] = __builtin_amdgcn_mfma_f32_16x16x32_bf16(af[i], bf[j], acc[i][j], 0, 0, 0);
    }

#pragma unroll
    for (int j = 0; j < 4; ++j) {
        const int col = bn0 + wn + j * 16 + lrow;
        const float bv = bias[col];
#pragma unroll
        for (int i = 0; i < 4; ++i) {
            const int row = bm0 + wm + i * 16 + lquad * 4;
#pragma unroll
            for (int r = 0; r < 4; ++r)
                out[(size_t)(row + r) * N_DIM + col] = acc[i][j][r] + bv;
        }
    }
}

extern "C" void kernel_launch(void* const* d_in, const int* in_sizes, int n_in,
                              void* d_out, int out_size, void* d_ws, size_t ws_size,
                              hipStream_t stream) {
    const float*    x     = (const float*)d_in[0];
    const float*    wh    = (const float*)d_in[1];
    const void*     wmed  = d_in[2];           // fp32 or fp16 — detected on device
    const int*      wl    = (const int*)d_in[3];
    const void*     hm    = d_in[4];           // int32 or uint8 — detected on device
    const void*     mm    = d_in[5];
    const float*    scale = (const float*)d_in[6];
    const float*    bias  = (const float*)d_in[7];
    float*          out   = (float*)d_out;

    unsigned short* wbf   = (unsigned short*)((char*)d_ws + 256);         // 32 MB
    unsigned short* xbf   = (unsigned short*)((char*)d_ws + 256 + (size_t)N_DIM * K_DIM * 2);
    const size_t need_full = 256 + (size_t)N_DIM * K_DIM * 2 + (size_t)M_DIM * K_DIM * 2;

    static bool attr_done = false;
    if (!attr_done) {
        (void)hipFuncSetAttribute(reinterpret_cast<const void*>(gemm256_kernel),
                                  hipFuncAttributeMaxDynamicSharedMemorySize, 131072);
        attr_done = true;
    }

    if (ws_size >= need_full) {
        // one fused prep launch: blocks [0,8192) build w, [8192,24576) convert x
        prep_kernel<<<24576, 256, 0, stream>>>(x, wh, wmed, wl, hm, mm, scale, wbf, xbf);
        gemm256_kernel<<<dim3(512), dim3(512), 131072, stream>>>(xbf, wbf, bias, out);
    } else {
        prep_kernel<<<8192, 256, 0, stream>>>(x, wh, wmed, wl, hm, mm, scale, wbf, wbf);
        dim3 grid(N_DIM / 128, M_DIM / 128);
        gemm_fused_kernel<<<grid, 256, 0, stream>>>(x, wbf, bias, out);
    }
}